// Round 1
// baseline (1132.539 us; speedup 1.0000x reference)
//
#include <hip/hip_runtime.h>

#define N_ROWS 32768
#define DIM 256
#define KCODES 4096
#define TM 64      // rows per block
#define TK 64      // codes per tile
#define DC 32      // d-chunk
#define LDP 68     // padded LDS stride (68%32=4 -> only 2-way read conflicts)

// ---------------- kernel 1: codebook squared norms ----------------
__global__ __launch_bounds__(256) void csq_kernel(const float* __restrict__ cb,
                                                  float* __restrict__ csq) {
    int code = blockIdx.x * 256 + threadIdx.x;
    if (code < KCODES) {
        const float4* row = (const float4*)(cb + (size_t)code * DIM);
        float s = 0.f;
        #pragma unroll 8
        for (int i = 0; i < DIM / 4; ++i) {
            float4 v = row[i];
            s += v.x * v.x + v.y * v.y + v.z * v.z + v.w * v.w;
        }
        csq[code] = s;
    }
}

// ---------------- kernel 2: fused distance + argmin ----------------
__global__ __launch_bounds__(256) void argmin_kernel(const float* __restrict__ x,
                                                     const float* __restrict__ cb,
                                                     const float* __restrict__ csq,
                                                     int* __restrict__ out_idx) {
    __shared__ __align__(16) float a_lds[DC][LDP];
    __shared__ __align__(16) float b_lds[DC][LDP];
    __shared__ float red_v[TM][16];
    __shared__ int   red_i[TM][16];

    const int tid = threadIdx.x;
    const int tc = tid & 15;   // code group (0..15) -> codes tc*4..tc*4+3
    const int tr = tid >> 4;   // row group  (0..15) -> rows  tr*4..tr*4+3
    const int rowBase = blockIdx.x * TM;

    float best_v[4] = {INFINITY, INFINITY, INFINITY, INFINITY};
    int   best_i[4] = {0, 0, 0, 0};

    for (int ct = 0; ct < KCODES / TK; ++ct) {
        const int codeBase = ct * TK;
        float acc[4][4];
        #pragma unroll
        for (int i = 0; i < 4; ++i)
            #pragma unroll
            for (int j = 0; j < 4; ++j) acc[i][j] = 0.f;

        for (int d0 = 0; d0 < DIM; d0 += DC) {
            // stage 64x32 chunks of A (rows) and B (codes), transposed into LDS
            #pragma unroll
            for (int h = 0; h < 2; ++h) {
                int f  = tid + h * 256;   // float4 slot 0..511
                int r  = f >> 3;          // row/code within tile (0..63)
                int dg = f & 7;           // which float4 along d (0..7)
                float4 av = *(const float4*)(x  + (size_t)(rowBase  + r) * DIM + d0 + dg * 4);
                float4 bv = *(const float4*)(cb + (size_t)(codeBase + r) * DIM + d0 + dg * 4);
                a_lds[dg * 4 + 0][r] = av.x; a_lds[dg * 4 + 1][r] = av.y;
                a_lds[dg * 4 + 2][r] = av.z; a_lds[dg * 4 + 3][r] = av.w;
                b_lds[dg * 4 + 0][r] = bv.x; b_lds[dg * 4 + 1][r] = bv.y;
                b_lds[dg * 4 + 2][r] = bv.z; b_lds[dg * 4 + 3][r] = bv.w;
            }
            __syncthreads();
            #pragma unroll
            for (int d = 0; d < DC; ++d) {
                float4 av = *(const float4*)&a_lds[d][tr * 4];
                float4 bv = *(const float4*)&b_lds[d][tc * 4];
                float ax[4] = {av.x, av.y, av.z, av.w};
                float bx[4] = {bv.x, bv.y, bv.z, bv.w};
                #pragma unroll
                for (int i = 0; i < 4; ++i)
                    #pragma unroll
                    for (int j = 0; j < 4; ++j)
                        acc[i][j] = fmaf(ax[i], bx[j], acc[i][j]);
            }
            __syncthreads();
        }

        // argmin update: dist = ||c||^2 - 2 x.c   (x_sq dropped, row-constant)
        float4 cs4 = *(const float4*)(csq + codeBase + tc * 4);
        float cs[4] = {cs4.x, cs4.y, cs4.z, cs4.w};
        #pragma unroll
        for (int i = 0; i < 4; ++i) {
            #pragma unroll
            for (int j = 0; j < 4; ++j) {
                float v = cs[j] - 2.0f * acc[i][j];
                int ci = codeBase + tc * 4 + j;
                if (v < best_v[i]) { best_v[i] = v; best_i[i] = ci; }
            }
        }
    }

    // cross-thread (16 code-groups) argmin reduction per row
    #pragma unroll
    for (int i = 0; i < 4; ++i) {
        red_v[tr * 4 + i][tc] = best_v[i];
        red_i[tr * 4 + i][tc] = best_i[i];
    }
    __syncthreads();
    if (tid < TM) {
        float bv = red_v[tid][0];
        int   bi = red_i[tid][0];
        #pragma unroll
        for (int t = 1; t < 16; ++t) {
            float v = red_v[tid][t];
            int ii  = red_i[tid][t];
            if (v < bv || (v == bv && ii < bi)) { bv = v; bi = ii; }
        }
        out_idx[rowBase + tid] = bi;
    }
}

// ---------------- kernel 3: gather quantized + loss partials ----------------
__global__ __launch_bounds__(256) void gather_loss_kernel(const float* __restrict__ x,
                                                          const float* __restrict__ cb,
                                                          const int* __restrict__ idx,
                                                          float* __restrict__ out,
                                                          float* __restrict__ partial) {
    __shared__ float sred[256];
    const int tid = threadIdx.x;
    const size_t g0 = (size_t)blockIdx.x * 256 + tid;  // float4 index
    const float4* x4 = (const float4*)x;
    const float4* c4 = (const float4*)cb;
    float4* o4 = (float4*)out;
    float s = 0.f;
    // 2097152 float4 total; 2048 blocks * 256 threads -> 4 iterations
    #pragma unroll
    for (int it = 0; it < 4; ++it) {
        size_t g = g0 + (size_t)it * (2048 * 256);
        int row = (int)(g >> 6);         // 64 float4 per row
        int k = idx[row];
        float4 q  = c4[(size_t)k * 64 + (g & 63)];
        float4 xv = x4[g];
        o4[g] = q;
        float dx = q.x - xv.x, dy = q.y - xv.y, dz = q.z - xv.z, dw = q.w - xv.w;
        s += dx * dx + dy * dy + dz * dz + dw * dw;
    }
    sred[tid] = s;
    __syncthreads();
    for (int off = 128; off > 0; off >>= 1) {
        if (tid < off) sred[tid] += sred[tid + off];
        __syncthreads();
    }
    if (tid == 0) partial[blockIdx.x] = sred[0];
}

// ---------------- kernel 4: finalize loss ----------------
__global__ __launch_bounds__(256) void finalize_kernel(const float* __restrict__ partial,
                                                       float* __restrict__ loss_out) {
    __shared__ float sred[256];
    const int tid = threadIdx.x;
    float s = 0.f;
    for (int i = tid; i < 2048; i += 256) s += partial[i];
    sred[tid] = s;
    __syncthreads();
    for (int off = 128; off > 0; off >>= 1) {
        if (tid < off) sred[tid] += sred[tid + off];
        __syncthreads();
    }
    // loss = (q_latent + 0.25*e_latent) = 1.25 * mean((q-x)^2)
    if (tid == 0) loss_out[0] = sred[0] * 1.25f / 8388608.0f;
}

extern "C" void kernel_launch(void* const* d_in, const int* in_sizes, int n_in,
                              void* d_out, int out_size, void* d_ws, size_t ws_size,
                              hipStream_t stream) {
    const float* x  = (const float*)d_in[0];
    const float* cb = (const float*)d_in[1];
    float* out = (float*)d_out;

    float* csq     = (float*)d_ws;                                    // 4096 f
    int*   idxbuf  = (int*)((char*)d_ws + 4096 * 4);                  // 32768 i
    float* partial = (float*)((char*)d_ws + 4096 * 4 + 32768 * 4);    // 2048 f

    csq_kernel<<<KCODES / 256, 256, 0, stream>>>(cb, csq);
    argmin_kernel<<<N_ROWS / TM, 256, 0, stream>>>(x, cb, csq, idxbuf);
    gather_loss_kernel<<<2048, 256, 0, stream>>>(x, cb, idxbuf, out, partial);
    finalize_kernel<<<1, 256, 0, stream>>>(partial, out + 8388608);
}

// Round 4
// 654.928 us; speedup vs baseline: 1.7293x; 1.7293x over previous
//
#include <hip/hip_runtime.h>

#define KCODES 4096
#define NROWS  32768
#define DIM    256
#define MB     128
#define LDA    264   // bf16 elems per LDS A row (256 + 8 pad); row stride 528B = 33*16B

typedef __attribute__((ext_vector_type(8))) short  short8;
typedef __attribute__((ext_vector_type(4))) float  float4v;

__device__ inline unsigned short f2bf(float f) {
    unsigned u = __float_as_uint(f);
    unsigned r = (u >> 16) & 1u;
    return (unsigned short)((u + 0x7FFFu + r) >> 16);   // RNE
}
__device__ inline float bf2f(unsigned short h) {
    return __uint_as_float(((unsigned)h) << 16);
}

// ---------------- kernel 0: codebook squared norms — VERBATIM R1 recipe ----------------
__global__ __launch_bounds__(256) void csq_kernel(const float* __restrict__ cb,
                                                  float* __restrict__ csq) {
    int code = blockIdx.x * 256 + threadIdx.x;
    if (code < KCODES) {
        const float4* row = (const float4*)(cb + (size_t)code * DIM);
        float s = 0.f;
        #pragma unroll 8
        for (int i = 0; i < DIM / 4; ++i) {
            float4 v = row[i];
            s += v.x * v.x + v.y * v.y + v.z * v.z + v.w * v.w;
        }
        csq[code] = s;
    }
}

// ---------------- kernel 1: cb -> bf16 hi/lo planes ----------------
__global__ __launch_bounds__(256) void convert_kernel(const float* __restrict__ cb,
                                                      unsigned short* __restrict__ cbh,
                                                      unsigned short* __restrict__ cbl) {
    const int wid = threadIdx.x >> 6, lane = threadIdx.x & 63;
    const int code = blockIdx.x * 4 + wid;
    float4 v = ((const float4*)(cb + (size_t)code * DIM))[lane];
    ushort4 h = { f2bf(v.x), f2bf(v.y), f2bf(v.z), f2bf(v.w) };
    ushort4 l = { f2bf(v.x - bf2f(h.x)), f2bf(v.y - bf2f(h.y)),
                  f2bf(v.z - bf2f(h.z)), f2bf(v.w - bf2f(h.w)) };
    *(ushort4*)(cbh + (size_t)code * DIM + lane * 4) = h;
    *(ushort4*)(cbl + (size_t)code * DIM + lane * 4) = l;
}

// ---------------- kernel 2: split-bf16 MFMA GEMM, top-2 per code-half -> 4 cands ----------------
__global__ __launch_bounds__(256, 1) void gemm_top4_kernel(const float* __restrict__ x,
                                                           const unsigned short* __restrict__ cbh,
                                                           const unsigned short* __restrict__ cbl,
                                                           const float* __restrict__ csq,
                                                           int* __restrict__ top4) {
    __shared__ unsigned short sAh[MB * LDA];
    __shared__ unsigned short sAl[MB * LDA];
    __shared__ int mI1[2][MB];
    __shared__ int mI2[2][MB];

    const int tid = threadIdx.x;
    const int lane = tid & 63, wid = tid >> 6;
    const int wm = wid >> 1, wn = wid & 1;      // 2x2 wave grid: 64 rows x 64 codes
    const int c = lane & 15, q = lane >> 4;
    const int rowBase = blockIdx.x * MB;

    // ---- stage A (x rows) as hi/lo bf16 into LDS, once ----
    const float4* x4 = (const float4*)x;
    #pragma unroll
    for (int i = 0; i < 32; ++i) {
        int f = tid + i * 256;
        int r = f >> 6, c4 = f & 63;
        float4 v = x4[(size_t)(rowBase + r) * 64 + c4];
        ushort4 h = { f2bf(v.x), f2bf(v.y), f2bf(v.z), f2bf(v.w) };
        ushort4 l = { f2bf(v.x - bf2f(h.x)), f2bf(v.y - bf2f(h.y)),
                      f2bf(v.z - bf2f(h.z)), f2bf(v.w - bf2f(h.w)) };
        *(ushort4*)&sAh[r * LDA + c4 * 4] = h;
        *(ushort4*)&sAl[r * LDA + c4 * 4] = l;
    }
    __syncthreads();

    // per-lane top-2 for the 16 (mi,r) row-slots
    float v1[16], v2[16]; int i1[16], i2[16];
    #pragma unroll
    for (int s = 0; s < 16; ++s) { v1[s] = INFINITY; v2[s] = INFINITY; i1[s] = 0x7FFFFFFF; i2[s] = 0x7FFFFFFF; }

    for (int ct = 0; ct < KCODES / 128; ++ct) {
        const int codeBase = ct * 128;
        float4v acc[4][4];
        #pragma unroll
        for (int mi = 0; mi < 4; ++mi)
            #pragma unroll
            for (int ni = 0; ni < 4; ++ni)
                #pragma unroll
                for (int e = 0; e < 4; ++e) acc[mi][ni][e] = 0.f;

        #pragma unroll
        for (int ks = 0; ks < 8; ++ks) {
            short8 ah[4], al[4], bh[4], bl[4];
            #pragma unroll
            for (int ni = 0; ni < 4; ++ni) {
                size_t off = (size_t)(codeBase + wn * 64 + ni * 16 + c) * DIM + ks * 32 + q * 8;
                bh[ni] = *(const short8*)(cbh + off);
                bl[ni] = *(const short8*)(cbl + off);
            }
            #pragma unroll
            for (int mi = 0; mi < 4; ++mi) {
                int aoff = (wm * 64 + mi * 16 + c) * LDA + ks * 32 + q * 8;
                ah[mi] = *(const short8*)&sAh[aoff];
                al[mi] = *(const short8*)&sAl[aoff];
            }
            #pragma unroll
            for (int mi = 0; mi < 4; ++mi)
                #pragma unroll
                for (int ni = 0; ni < 4; ++ni) {
                    acc[mi][ni] = __builtin_amdgcn_mfma_f32_16x16x32_bf16(ah[mi], bh[ni], acc[mi][ni], 0, 0, 0);
                    acc[mi][ni] = __builtin_amdgcn_mfma_f32_16x16x32_bf16(ah[mi], bl[ni], acc[mi][ni], 0, 0, 0);
                    acc[mi][ni] = __builtin_amdgcn_mfma_f32_16x16x32_bf16(al[mi], bh[ni], acc[mi][ni], 0, 0, 0);
                }
        }

        // ---- epilogue: dist = csq - 2*dot ; top-2 update ----
        float cs[4];
        #pragma unroll
        for (int ni = 0; ni < 4; ++ni) cs[ni] = csq[codeBase + wn * 64 + ni * 16 + c];
        #pragma unroll
        for (int mi = 0; mi < 4; ++mi)
            #pragma unroll
            for (int r = 0; r < 4; ++r) {
                const int s = mi * 4 + r;
                #pragma unroll
                for (int ni = 0; ni < 4; ++ni) {
                    float d = fmaf(-2.f, acc[mi][ni][r], cs[ni]);
                    int   k = codeBase + wn * 64 + ni * 16 + c;
                    bool b1 = d < v1[s];
                    bool b2 = d < v2[s];
                    v2[s] = b1 ? v1[s] : (b2 ? d : v2[s]);
                    i2[s] = b1 ? i1[s] : (b2 ? k : i2[s]);
                    v1[s] = b1 ? d : v1[s];
                    i1[s] = b1 ? k : i1[s];
                }
            }
    }

    // ---- butterfly lex-merge of top-2 across the 16 code-lanes (per half) ----
    #pragma unroll
    for (int s = 0; s < 16; ++s) {
        float a1 = v1[s], a2 = v2[s]; int b1 = i1[s], b2 = i2[s];
        #pragma unroll
        for (int m = 1; m < 16; m <<= 1) {
            float w1 = __shfl_xor(a1, m), w2 = __shfl_xor(a2, m);
            int   j1 = __shfl_xor(b1, m), j2 = __shfl_xor(b2, m);
            bool lt = (w1 < a1) || (w1 == a1 && j1 < b1);
            float f1 = lt ? w1 : a1;  int g1 = lt ? j1 : b1;   // merged first
            float o1 = lt ? a1 : w1;  int p1 = lt ? b1 : j1;   // loser of firsts
            float o2 = lt ? w2 : a2;  int p2 = lt ? j2 : b2;   // winner's second
            bool lt2 = (o1 < o2) || (o1 == o2 && p1 < p2);
            a1 = f1; b1 = g1;
            a2 = lt2 ? o1 : o2; b2 = lt2 ? p1 : p2;
        }
        if (c == 0) {
            int row = wm * 64 + (s >> 2) * 16 + q * 4 + (s & 3);
            mI1[wn][row] = b1;
            mI2[wn][row] = b2;
        }
    }
    __syncthreads();

    // ---- emit 4 candidates per row (top-2 of each code half) ----
    if (tid < MB) {
        size_t rg = (size_t)(rowBase + tid) * 4;
        top4[rg + 0] = mI1[0][tid];
        top4[rg + 1] = mI2[0][tid];
        top4[rg + 2] = mI1[1][tid];
        top4[rg + 3] = mI2[1][tid];
    }
}

// ---------------- kernel 3: rescore with R1's exact fp32 recipe + gather + loss ----------------
__global__ __launch_bounds__(256) void rescore_kernel(const float* __restrict__ x,
                                                      const float* __restrict__ cb,
                                                      const float* __restrict__ csq,
                                                      const int* __restrict__ top4,
                                                      float* __restrict__ out,
                                                      float* __restrict__ partial) {
    __shared__ float sx[64 * 256];   // 64 rows of x, raw fp32
    __shared__ float rv[64][4];
    __shared__ int   rk[64][4];
    __shared__ int   pick[64];
    __shared__ float sred[256];

    const int tid = threadIdx.x;
    const int rowBase = blockIdx.x * 64;
    const float4* x4 = (const float4*)x;
    const float4* c4 = (const float4*)cb;

    // stage 64 x-rows (coalesced float4)
    #pragma unroll
    for (int i = 0; i < 16; ++i) {
        int g = tid + i * 256;
        ((float4*)sx)[g] = x4[(size_t)rowBase * 64 + g];
    }
    __syncthreads();

    // one thread per (row, candidate): serial fmaf chain, ascending d (bit-identical to R1)
    {
        const int r = tid >> 2, ci = tid & 3;
        const int k = top4[(size_t)(rowBase + r) * 4 + ci];
        const float4* cr = c4 + (size_t)k * 64;
        const float4* xr = (const float4*)sx + r * 64;
        float acc = 0.f;
        for (int d4 = 0; d4 < 64; ++d4) {
            float4 cv = cr[d4];
            float4 xv = xr[d4];
            acc = fmaf(xv.x, cv.x, acc);
            acc = fmaf(xv.y, cv.y, acc);
            acc = fmaf(xv.z, cv.z, acc);
            acc = fmaf(xv.w, cv.w, acc);
        }
        float cs = csq[k];
        float v = cs - 2.0f * acc;    // same expression as R1
        rv[r][ci] = v;
        rk[r][ci] = k;
    }
    __syncthreads();

    // lex-min over the 4 candidates (R1's comparator)
    if (tid < 64) {
        float bv = rv[tid][0];
        int   bi = rk[tid][0];
        #pragma unroll
        for (int t = 1; t < 4; ++t) {
            float v = rv[tid][t];
            int  ii = rk[tid][t];
            if (v < bv || (v == bv && ii < bi)) { bv = v; bi = ii; }
        }
        pick[tid] = bi;
    }
    __syncthreads();

    // gather + loss partial
    float s = 0.f;
    #pragma unroll
    for (int i = 0; i < 16; ++i) {
        int g = tid + i * 256;
        int r = g >> 6, col = g & 63;
        int k = pick[r];
        float4 cv = c4[(size_t)k * 64 + col];
        float4 xv = ((const float4*)sx)[g];
        ((float4*)out)[(size_t)rowBase * 64 + g] = cv;
        float dx = cv.x - xv.x, dy = cv.y - xv.y, dz = cv.z - xv.z, dw = cv.w - xv.w;
        s += dx * dx + dy * dy + dz * dz + dw * dw;
    }
    sred[tid] = s;
    __syncthreads();
    for (int off = 128; off > 0; off >>= 1) {
        if (tid < off) sred[tid] += sred[tid + off];
        __syncthreads();
    }
    if (tid == 0) partial[blockIdx.x] = sred[0];
}

// ---------------- kernel 4: finalize loss ----------------
__global__ __launch_bounds__(256) void finalize_kernel(const float* __restrict__ partial,
                                                       float* __restrict__ loss_out) {
    __shared__ float sred[256];
    const int tid = threadIdx.x;
    float s = 0.f;
    for (int i = tid; i < 512; i += 256) s += partial[i];
    sred[tid] = s;
    __syncthreads();
    for (int off = 128; off > 0; off >>= 1) {
        if (tid < off) sred[tid] += sred[tid + off];
        __syncthreads();
    }
    if (tid == 0) loss_out[0] = sred[0] * 1.25f / 8388608.0f;
}

extern "C" void kernel_launch(void* const* d_in, const int* in_sizes, int n_in,
                              void* d_out, int out_size, void* d_ws, size_t ws_size,
                              hipStream_t stream) {
    const float* x  = (const float*)d_in[0];
    const float* cb = (const float*)d_in[1];
    float* out = (float*)d_out;

    char* ws = (char*)d_ws;
    unsigned short* cbh = (unsigned short*)ws;                        // 2 MB
    unsigned short* cbl = (unsigned short*)(ws + 2097152);            // 2 MB
    float* csq          = (float*)(ws + 4194304);                     // 16 KB
    int*   top4         = (int*)(ws + 4194304 + 16384);               // 512 KB
    float* partial      = (float*)(ws + 4194304 + 16384 + 524288);    // 2 KB

    csq_kernel<<<KCODES / 256, 256, 0, stream>>>(cb, csq);
    convert_kernel<<<KCODES / 4, 256, 0, stream>>>(cb, cbh, cbl);
    gemm_top4_kernel<<<NROWS / MB, 256, 0, stream>>>(x, cbh, cbl, csq, top4);
    rescore_kernel<<<NROWS / 64, 256, 0, stream>>>(x, cb, csq, top4, out, partial);
    finalize_kernel<<<1, 256, 0, stream>>>(partial, out + 8388608);
}